// Round 1
// baseline (72.766 us; speedup 1.0000x reference)
//
#include <hip/hip_runtime.h>
#include <math.h>

#define HID 1024
#define SEQ 4096
#define NB 16
#define CHUNK 64
#define NCHUNK (SEQ / CHUNK)   // 64

// ---------------------------------------------------------------------------
// Kernel A: partial of hp·v_p per (batch, 64-column segment), fp64 accumulation.
// grid (16 batches, 16 jsegs), block 256.  hp[j] = tanh(sum_h t[h]*W_p[h,j] + b_p[j])
// pPart[b*16+jseg] = sum_{j in seg} hp[j]*v_p[j]
// ---------------------------------------------------------------------------
__global__ __launch_bounds__(256) void kA(const float* __restrict__ tgt,
                                          const float* __restrict__ Wp,
                                          const float* __restrict__ bp,
                                          const float* __restrict__ vp,
                                          double* __restrict__ pPart) {
  __shared__ float tl[HID];
  __shared__ double red[4][64];
  const int b = blockIdx.x;
  const int jseg = blockIdx.y;
  const int j0 = jseg * 64;
  const int tid = threadIdx.x;

  // stage t[b,:] into LDS (coalesced)
  #pragma unroll
  for (int k = 0; k < 4; ++k) tl[tid + k * 256] = tgt[b * HID + tid + k * 256];
  __syncthreads();

  const int jl  = tid & 63;   // column within segment
  const int hp4 = tid >> 6;   // h-quarter 0..3
  double acc = 0.0;
  const float* wcol = Wp + (size_t)(hp4 * 256) * HID + j0 + jl;
  for (int i = 0; i < 256; ++i) {
    acc += (double)tl[hp4 * 256 + i] * (double)wcol[(size_t)i * HID];
  }
  red[hp4][jl] = acc;
  __syncthreads();

  if (tid < 64) {
    double s = red[0][tid] + red[1][tid] + red[2][tid] + red[3][tid];
    double hpv = tanh(s + (double)bp[j0 + tid]);
    double val = hpv * (double)vp[j0 + tid];
    #pragma unroll
    for (int off = 32; off; off >>= 1) val += __shfl_xor(val, off);
    if (tid == 0) pPart[b * 16 + jseg] = val;
  }
}

// ---------------------------------------------------------------------------
// Kernel B: fused score+exp+gauss+context partial, single read of src.
// grid 1024 (16 batches x 64 chunks of 64 rows), block 256 (4 waves x 16 rows).
// Lane l owns columns k*256 + 4l + j (k=0..3, j=0..3)  -> perfectly coalesced
// float4 loads; full row dot via wave shuffle reduce; ctx partial in registers.
// ---------------------------------------------------------------------------
__global__ __launch_bounds__(256) void kB(const float* __restrict__ src,
                                          const float* __restrict__ tgt,
                                          const double* __restrict__ pPart,
                                          const float* __restrict__ bv,
                                          float* __restrict__ zPart,
                                          float* __restrict__ ctxPart) {
  const int chunk = blockIdx.x;      // 0..1023
  const int b = chunk >> 6;
  const int c = chunk & 63;
  const int s0 = c * CHUNK;
  const int tid = threadIdx.x;
  const int wave = tid >> 6;
  const int lane = tid & 63;

  // p for this batch (deterministic fp64 sum of 16 partials)
  double lg = (double)bv[0];
  #pragma unroll
  for (int i = 0; i < 16; ++i) lg += pPart[b * 16 + i];
  const float pb = (float)(4096.0 / (1.0 + exp(-lg)));

  // target fragment (16 floats per lane)
  float4 tf[4];
  const float4* tg4 = (const float4*)(tgt + b * HID);
  #pragma unroll
  for (int k = 0; k < 4; ++k) tf[k] = tg4[k * 64 + lane];

  float4 acc[4];
  #pragma unroll
  for (int k = 0; k < 4; ++k) acc[k] = make_float4(0.f, 0.f, 0.f, 0.f);
  float z = 0.f;

  for (int r = 0; r < 16; ++r) {
    const int s = s0 + wave * 16 + r;
    const float4* srow = (const float4*)(src + ((size_t)b * SEQ + s) * HID);
    float4 x[4];
    #pragma unroll
    for (int k = 0; k < 4; ++k) x[k] = srow[k * 64 + lane];

    float dot = 0.f;
    #pragma unroll
    for (int k = 0; k < 4; ++k) {
      dot = fmaf(x[k].x, tf[k].x, dot);
      dot = fmaf(x[k].y, tf[k].y, dot);
      dot = fmaf(x[k].z, tf[k].z, dot);
      dot = fmaf(x[k].w, tf[k].w, dot);
    }
    #pragma unroll
    for (int off = 32; off; off >>= 1) dot += __shfl_xor(dot, off);

    const float w = expf(dot * 0.03125f);                 // exp(score/sqrt(H))
    const float ds = (float)s - pb;
    const float g = expf(ds * ds * (-1.0f / 2048.0f));    // gaussian window
    z += w;
    const float wg = w * g;
    #pragma unroll
    for (int k = 0; k < 4; ++k) {
      acc[k].x = fmaf(wg, x[k].x, acc[k].x);
      acc[k].y = fmaf(wg, x[k].y, acc[k].y);
      acc[k].z = fmaf(wg, x[k].z, acc[k].z);
      acc[k].w = fmaf(wg, x[k].w, acc[k].w);
    }
  }

  // combine 4 waves via LDS
  __shared__ float lctx[4][HID];
  __shared__ float lz[4];
  #pragma unroll
  for (int k = 0; k < 4; ++k)
    *(float4*)&lctx[wave][k * 256 + lane * 4] = acc[k];
  if (lane == 0) lz[wave] = z;
  __syncthreads();

  float4 s4 = make_float4(0.f, 0.f, 0.f, 0.f);
  #pragma unroll
  for (int w2 = 0; w2 < 4; ++w2) {
    float4 v = *(const float4*)&lctx[w2][tid * 4];
    s4.x += v.x; s4.y += v.y; s4.z += v.z; s4.w += v.w;
  }
  ((float4*)ctxPart)[(size_t)chunk * 256 + tid] = s4;
  if (tid == 0) zPart[chunk] = lz[0] + lz[1] + lz[2] + lz[3];
}

// ---------------------------------------------------------------------------
// Kernel C: combine chunk partials, divide by Z.  grid 16, block 256.
// ---------------------------------------------------------------------------
__global__ __launch_bounds__(256) void kC(const float* __restrict__ zPart,
                                          const float* __restrict__ ctxPart,
                                          float* __restrict__ out) {
  const int b = blockIdx.x;
  const int tid = threadIdx.x;
  float Z = 0.f;
  for (int c = 0; c < NCHUNK; ++c) Z += zPart[b * NCHUNK + c];
  const float inv = 1.0f / Z;
  float4 s4 = make_float4(0.f, 0.f, 0.f, 0.f);
  const float4* cp = (const float4*)ctxPart;
  for (int c = 0; c < NCHUNK; ++c) {
    float4 v = cp[((size_t)(b * NCHUNK + c)) * 256 + tid];
    s4.x += v.x; s4.y += v.y; s4.z += v.z; s4.w += v.w;
  }
  ((float4*)out)[b * 256 + tid] =
      make_float4(s4.x * inv, s4.y * inv, s4.z * inv, s4.w * inv);
}

// ---------------------------------------------------------------------------
extern "C" void kernel_launch(void* const* d_in, const int* in_sizes, int n_in,
                              void* d_out, int out_size, void* d_ws, size_t ws_size,
                              hipStream_t stream) {
  const float* src = (const float*)d_in[0];   // (16, 4096, 1024)
  const float* tgt = (const float*)d_in[1];   // (16, 1024)
  const float* Wp  = (const float*)d_in[2];   // (1024, 1024)
  const float* bp  = (const float*)d_in[3];   // (1024,)
  const float* vp  = (const float*)d_in[4];   // (1024,)
  const float* bv  = (const float*)d_in[5];   // scalar
  float* out = (float*)d_out;

  // workspace layout (all regions fully rewritten every call; no init needed)
  double* pPart  = (double*)d_ws;                          // 256 doubles (2 KB)
  float* zPart   = (float*)((char*)d_ws + 4096);           // 1024 floats (4 KB)
  float* ctxPart = (float*)((char*)d_ws + 8192);           // 1024*1024 floats (4 MB)

  kA<<<dim3(NB, 16), 256, 0, stream>>>(tgt, Wp, bp, vp, pPart);
  kB<<<NB * NCHUNK, 256, 0, stream>>>(src, tgt, pPart, bv, zPart, ctxPart);
  kC<<<NB, 256, 0, stream>>>(zPart, ctxPart, out);
}

// Round 3
// 69.224 us; speedup vs baseline: 1.0512x; 1.0512x over previous
//
#include <hip/hip_runtime.h>
#include <math.h>

#define HID 1024
#define SEQ 4096
#define NB 16
#define CHUNK 64
#define NCHUNK (SEQ / CHUNK)   // 64

typedef float floatx4 __attribute__((ext_vector_type(4)));

// ---------------------------------------------------------------------------
// Kernel A: partial of hp·v_p per (batch, 64-column segment), fp64 accumulation.
// grid (16 batches, 16 jsegs), block 256.
// hp[j] = tanh(sum_h t[h]*W_p[h,j] + b_p[j]);  pPart[b*16+jseg] = sum_seg hp[j]*v_p[j]
// 4-way unrolled fp64 accumulators to break the dependency chain.
// ---------------------------------------------------------------------------
__global__ __launch_bounds__(256) void kA(const float* __restrict__ tgt,
                                          const float* __restrict__ Wp,
                                          const float* __restrict__ bp,
                                          const float* __restrict__ vp,
                                          double* __restrict__ pPart) {
  __shared__ float tl[HID];
  __shared__ double red[4][64];
  const int b = blockIdx.x;
  const int jseg = blockIdx.y;
  const int j0 = jseg * 64;
  const int tid = threadIdx.x;

  #pragma unroll
  for (int k = 0; k < 4; ++k) tl[tid + k * 256] = tgt[b * HID + tid + k * 256];
  __syncthreads();

  const int jl  = tid & 63;   // column within segment
  const int hp4 = tid >> 6;   // h-quarter 0..3
  double a0 = 0.0, a1 = 0.0, a2 = 0.0, a3 = 0.0;
  const float* wcol = Wp + (size_t)(hp4 * 256) * HID + j0 + jl;
  const float* tq = tl + hp4 * 256;
  for (int i = 0; i < 256; i += 4) {
    a0 += (double)tq[i + 0] * (double)wcol[(size_t)(i + 0) * HID];
    a1 += (double)tq[i + 1] * (double)wcol[(size_t)(i + 1) * HID];
    a2 += (double)tq[i + 2] * (double)wcol[(size_t)(i + 2) * HID];
    a3 += (double)tq[i + 3] * (double)wcol[(size_t)(i + 3) * HID];
  }
  red[hp4][jl] = (a0 + a1) + (a2 + a3);
  __syncthreads();

  if (tid < 64) {
    double s = red[0][tid] + red[1][tid] + red[2][tid] + red[3][tid];
    double hpv = tanh(s + (double)bp[j0 + tid]);
    double val = hpv * (double)vp[j0 + tid];
    #pragma unroll
    for (int off = 32; off; off >>= 1) val += __shfl_xor(val, off);
    if (tid == 0) pPart[b * 16 + jseg] = val;
  }
}

// ---------------------------------------------------------------------------
// Kernel B: fused score+exp+gauss+context partial, single streamed read of src.
// grid 1024 (16 batches x 64 chunks of 64 rows), block 256 (4 waves x 16 rows).
// Explicit row double-buffer: row r+1's loads issue before row r's reduce,
// keeping >=8KB per wave in flight. src loads are non-temporal (zero reuse).
// ---------------------------------------------------------------------------
__device__ __forceinline__ float4 nt_load4(const float* p) {
  floatx4 v = __builtin_nontemporal_load((const floatx4*)p);
  return make_float4(v.x, v.y, v.z, v.w);
}

__global__ __launch_bounds__(256) void kB(const float* __restrict__ src,
                                          const float* __restrict__ tgt,
                                          const double* __restrict__ pPart,
                                          const float* __restrict__ bv,
                                          float* __restrict__ zPart,
                                          float* __restrict__ ctxPart) {
  const int chunk = blockIdx.x;      // 0..1023
  const int b = chunk >> 6;
  const int c = chunk & 63;
  const int s0 = c * CHUNK;
  const int tid = threadIdx.x;
  const int wave = tid >> 6;
  const int lane = tid & 63;

  // finalize p for this batch (deterministic fp64 sum of 16 partials)
  double lg = (double)bv[0];
  #pragma unroll
  for (int i = 0; i < 16; ++i) lg += pPart[b * 16 + i];
  const float pb = (float)(4096.0 / (1.0 + exp(-lg)));

  // target fragment (16 floats per lane)
  float4 tf[4];
  const float4* tg4 = (const float4*)(tgt + b * HID);
  #pragma unroll
  for (int k = 0; k < 4; ++k) tf[k] = tg4[k * 64 + lane];

  float4 acc[4];
  #pragma unroll
  for (int k = 0; k < 4; ++k) acc[k] = make_float4(0.f, 0.f, 0.f, 0.f);
  float z = 0.f;

  const int srow0 = s0 + wave * 16;
  const float* base = src + ((size_t)b * SEQ + srow0) * HID;

  float4 x[2][4];
  #pragma unroll
  for (int k = 0; k < 4; ++k) x[0][k] = nt_load4(base + (k * 64 + lane) * 4);

  #pragma unroll
  for (int r = 0; r < 16; ++r) {
    const int cur = r & 1, nxt = cur ^ 1;
    if (r + 1 < 16) {
      #pragma unroll
      for (int k = 0; k < 4; ++k)
        x[nxt][k] = nt_load4(base + ((r + 1) * 256 + k * 64 + lane) * 4);
    }

    float dot = 0.f;
    #pragma unroll
    for (int k = 0; k < 4; ++k) {
      dot = fmaf(x[cur][k].x, tf[k].x, dot);
      dot = fmaf(x[cur][k].y, tf[k].y, dot);
      dot = fmaf(x[cur][k].z, tf[k].z, dot);
      dot = fmaf(x[cur][k].w, tf[k].w, dot);
    }
    #pragma unroll
    for (int off = 32; off; off >>= 1) dot += __shfl_xor(dot, off);

    const float w = expf(dot * 0.03125f);                 // exp(score/sqrt(H))
    const float ds = (float)(srow0 + r) - pb;
    const float g = expf(ds * ds * (-1.0f / 2048.0f));    // gaussian window
    z += w;
    const float wg = w * g;
    #pragma unroll
    for (int k = 0; k < 4; ++k) {
      acc[k].x = fmaf(wg, x[cur][k].x, acc[k].x);
      acc[k].y = fmaf(wg, x[cur][k].y, acc[k].y);
      acc[k].z = fmaf(wg, x[cur][k].z, acc[k].z);
      acc[k].w = fmaf(wg, x[cur][k].w, acc[k].w);
    }
  }

  // combine 4 waves via LDS
  __shared__ float lctx[4][HID];
  __shared__ float lz[4];
  #pragma unroll
  for (int k = 0; k < 4; ++k)
    *(float4*)&lctx[wave][k * 256 + lane * 4] = acc[k];
  if (lane == 0) lz[wave] = z;
  __syncthreads();

  float4 s4 = make_float4(0.f, 0.f, 0.f, 0.f);
  #pragma unroll
  for (int w2 = 0; w2 < 4; ++w2) {
    float4 v = *(const float4*)&lctx[w2][tid * 4];
    s4.x += v.x; s4.y += v.y; s4.z += v.z; s4.w += v.w;
  }
  ((float4*)ctxPart)[(size_t)chunk * 256 + tid] = s4;
  if (tid == 0) zPart[chunk] = lz[0] + lz[1] + lz[2] + lz[3];
}

// ---------------------------------------------------------------------------
// Kernel C: combine chunk partials, divide by Z.  grid 16, block 256.
// ---------------------------------------------------------------------------
__global__ __launch_bounds__(256) void kC(const float* __restrict__ zPart,
                                          const float* __restrict__ ctxPart,
                                          float* __restrict__ out) {
  const int b = blockIdx.x;
  const int tid = threadIdx.x;
  float Z = 0.f;
  for (int c = 0; c < NCHUNK; ++c) Z += zPart[b * NCHUNK + c];
  const float inv = 1.0f / Z;
  float4 s4 = make_float4(0.f, 0.f, 0.f, 0.f);
  const float4* cp = (const float4*)ctxPart;
  for (int c = 0; c < NCHUNK; ++c) {
    float4 v = cp[((size_t)(b * NCHUNK + c)) * 256 + tid];
    s4.x += v.x; s4.y += v.y; s4.z += v.z; s4.w += v.w;
  }
  ((float4*)out)[b * 256 + tid] =
      make_float4(s4.x * inv, s4.y * inv, s4.z * inv, s4.w * inv);
}

// ---------------------------------------------------------------------------
extern "C" void kernel_launch(void* const* d_in, const int* in_sizes, int n_in,
                              void* d_out, int out_size, void* d_ws, size_t ws_size,
                              hipStream_t stream) {
  const float* src = (const float*)d_in[0];   // (16, 4096, 1024)
  const float* tgt = (const float*)d_in[1];   // (16, 1024)
  const float* Wp  = (const float*)d_in[2];   // (1024, 1024)
  const float* bp  = (const float*)d_in[3];   // (1024,)
  const float* vp  = (const float*)d_in[4];   // (1024,)
  const float* bv  = (const float*)d_in[5];   // scalar
  float* out = (float*)d_out;

  // workspace layout (all regions fully rewritten every call; no init needed)
  double* pPart  = (double*)d_ws;                          // 256 doubles (2 KB)
  float* zPart   = (float*)((char*)d_ws + 4096);           // 1024 floats (4 KB)
  float* ctxPart = (float*)((char*)d_ws + 8192);           // 1024*1024 floats (4 MB)

  kA<<<dim3(NB, 16), 256, 0, stream>>>(tgt, Wp, bp, vp, pPart);
  kB<<<NB * NCHUNK, 256, 0, stream>>>(src, tgt, pPart, bv, zPart, ctxPart);
  kC<<<NB, 256, 0, stream>>>(zPart, ctxPart, out);
}